// Round 5
// baseline (2235.062 us; speedup 1.0000x reference)
//
#include <hip/hip_runtime.h>

typedef _Float16 f16x8 __attribute__((ext_vector_type(8)));
typedef _Float16 f16x4 __attribute__((ext_vector_type(4)));
typedef float f32x4 __attribute__((ext_vector_type(4)));

#define BN   65536   // B*N = 16*4096
#define MSZ  4096
#define TOPK 8

#define MFMA(a, b, c) __builtin_amdgcn_mfma_f32_16x16x32_f16(a, b, c, 0, 0, 0)

// ---------------------------------------------------------------------------
// Prep: fp32 -> fp16 flat convert (keys)
// ---------------------------------------------------------------------------
__global__ void cvt_f16(const float* __restrict__ src, _Float16* __restrict__ dst,
                        int n) {
    int i = blockIdx.x * 256 + threadIdx.x;
    if (i < n) dst[i] = (_Float16)src[i];
}

// ---------------------------------------------------------------------------
// Prep: dst[n*K + k] = (f16)src[k*N + n]  (W is K x N row-major; dst rows are
// k-contiguous per output column n — the MFMA B-operand layout)
// ---------------------------------------------------------------------------
__global__ void cvt_transpose(const float* __restrict__ src, _Float16* __restrict__ dst,
                              int K, int N) {
    int i = blockIdx.x * 256 + threadIdx.x;
    if (i < K * N) {
        int k = i / N, n = i - k * N;
        dst[n * K + k] = (_Float16)src[i];
    }
}

// ---------------------------------------------------------------------------
// Fully fused: proj -> sim -> top8 -> softmax -> gather -> MLP1 -> MLP2.
// 32 rows / block, 256 threads (4 waves). fp32 in/out; fp16 MFMA operands
// (fp16 mantissa = 10 bits: 8x less rounding error than bf16 — the round-4
// absmax 0.186 was softmax-weight error from bf16 sim; /8 -> ~0.023).
// MFMA 16x16x32_f16: A[m=lane&15][k=quad*8+j]; B[k][n]: n=lane&15, k=quad*8+j
// (W^T rows / keys rows are k-contiguous 16B loads); D: col=lane&15, row=quad*4+reg.
// LDS: AA[32][520] f16 holds [query(0:256) | qproj->retrieved(256:512)];
// MLP1 output overwrites AA[:,0:256]. Ubuf time-shares Ss / Ms+Mi.
// ---------------------------------------------------------------------------
__global__ __launch_bounds__(256) void fused_all(
        const float*    __restrict__ query,   // BN x 256 fp32
        const _Float16* __restrict__ keysH,   // 4096 x 256 f16 (ws)
        const float*    __restrict__ vals,    // 4096 x 256 fp32
        const _Float16* __restrict__ WqT,     // 256 x 256 f16 (ws, transposed)
        const float*    __restrict__ bq,
        const _Float16* __restrict__ W1T,     // 256 x 512 f16 (ws, transposed)
        const float*    __restrict__ b1,
        const _Float16* __restrict__ W2T,     // 256 x 256 f16 (ws, transposed)
        const float*    __restrict__ b2,
        float* __restrict__ out)              // BN x 256 fp32
{
    constexpr int ROWS = 32;
    __shared__ __attribute__((aligned(16))) _Float16 AA[ROWS][520];  // 33280 B
    __shared__ __attribute__((aligned(16))) char Ubuf[16384];
    __shared__ float Fs[ROWS][TOPK];
    __shared__ int   Fi[ROWS][TOPK];
    __shared__ int   Hd[ROWS][8];

    float (*Ss)[68]   = (float (*)[68])Ubuf;            // [32][68] sim chunk
    float (*Ms)[8][8] = (float (*)[8][8])Ubuf;          // top-8 dump (scores)
    int   (*Mi)[8][8] = (int (*)[8][8])(Ubuf + 8192);   // top-8 dump (indices)

    const int tid  = threadIdx.x;
    const int lane = tid & 63, quad = lane >> 4, l16 = lane & 15, wave = tid >> 6;
    const size_t row0 = (size_t)blockIdx.x * ROWS;

    // ---- P0: stage 32 query rows (fp32 -> f16) into AA[:, 0:256) ----
    for (int v = tid; v < 2048; v += 256) {          // 2048 = 32 rows * 64 chunks
        int r = v >> 6, c = (v & 63) * 4;
        float4 f = *(const float4*)(query + (row0 + r) * 256 + c);
        f16x4 h = {(_Float16)f.x, (_Float16)f.y, (_Float16)f.z, (_Float16)f.w};
        *(f16x4*)&AA[r][c] = h;
    }
    __syncthreads();

    // ---- P1: qproj = query @ Wq + bq -> AA[:, 256:512) (disjoint region) ----
    {
        f32x4 acc[2][4];
#pragma unroll
        for (int rt = 0; rt < 2; ++rt)
#pragma unroll
            for (int nt = 0; nt < 4; ++nt)
                acc[rt][nt] = (f32x4){0.f, 0.f, 0.f, 0.f};
#pragma unroll
        for (int kf = 0; kf < 8; ++kf) {
            f16x8 a0 = *(const f16x8*)&AA[l16][kf * 32 + quad * 8];
            f16x8 a1 = *(const f16x8*)&AA[l16 + 16][kf * 32 + quad * 8];
#pragma unroll
            for (int nt = 0; nt < 4; ++nt) {
                int n0 = wave * 16 + nt * 64;
                f16x8 b = *(const f16x8*)(WqT + (size_t)(n0 + l16) * 256 + kf * 32 + quad * 8);
                acc[0][nt] = MFMA(a0, b, acc[0][nt]);
                acc[1][nt] = MFMA(a1, b, acc[1][nt]);
            }
        }
#pragma unroll
        for (int nt = 0; nt < 4; ++nt) {
            int col = wave * 16 + nt * 64 + l16;
            float bv = bq[col];
#pragma unroll
            for (int rt = 0; rt < 2; ++rt)
#pragma unroll
                for (int r = 0; r < 4; ++r)
                    AA[rt * 16 + quad * 4 + r][256 + col] = (_Float16)(acc[rt][nt][r] + bv);
        }
    }
    __syncthreads();

    // ---- P2: sim = qproj @ keys^T, streaming top-8 ----
    f16x8 af0[8], af1[8];
#pragma unroll
    for (int nk = 0; nk < 8; ++nk) {
        af0[nk] = *(const f16x8*)&AA[l16][256 + nk * 32 + quad * 8];
        af1[nk] = *(const f16x8*)&AA[l16 + 16][256 + nk * 32 + quad * 8];
    }

    float ts[8];
    int   ti[8];
#pragma unroll
    for (int jj = 0; jj < 8; ++jj) { ts[jj] = -INFINITY; ti[jj] = 0x7fffffff; }

    const int mrow = tid >> 3;  // 0..31
    const int msub = tid & 7;   // 0..7

    for (int m0 = 0; m0 < MSZ; m0 += 64) {
        f32x4 acc0 = {0.f, 0.f, 0.f, 0.f};
        f32x4 acc1 = {0.f, 0.f, 0.f, 0.f};
        const _Float16* bp = keysH + (size_t)(m0 + wave * 16 + l16) * 256 + quad * 8;
#pragma unroll
        for (int nk = 0; nk < 8; ++nk) {
            f16x8 b = *(const f16x8*)(bp + nk * 32);
            acc0 = MFMA(af0[nk], b, acc0);
            acc1 = MFMA(af1[nk], b, acc1);
        }
#pragma unroll
        for (int r = 0; r < 4; ++r) {
            Ss[quad * 4 + r][wave * 16 + l16]      = acc0[r];
            Ss[16 + quad * 4 + r][wave * 16 + l16] = acc1[r];
        }
        __syncthreads();

        // top-8 maintenance: 8 threads/row, 8 candidates each (tie: low idx)
#pragma unroll
        for (int k = 0; k < 8; ++k) {
            int c = k * 8 + msub;
            float s = Ss[mrow][c];
            int idx = m0 + c;
            if (s > ts[7] || (s == ts[7] && idx < ti[7])) {
                ts[7] = s; ti[7] = idx;
#pragma unroll
                for (int p = 7; p > 0; --p) {
                    bool sw = (ts[p] > ts[p - 1]) ||
                              (ts[p] == ts[p - 1] && ti[p] < ti[p - 1]);
                    if (sw) {
                        float tf = ts[p]; ts[p] = ts[p - 1]; ts[p - 1] = tf;
                        int   tg = ti[p]; ti[p] = ti[p - 1]; ti[p - 1] = tg;
                    }
                }
            }
        }
        __syncthreads();  // protect Ss (and the Ms/Mi dump after the loop)
    }

    // ---- dump per-thread sorted top-8 (overlays Ss) ----
#pragma unroll
    for (int jj = 0; jj < 8; ++jj) { Ms[mrow][msub][jj] = ts[jj]; Mi[mrow][msub][jj] = ti[jj]; }
    __syncthreads();

    // ---- merge 8 sorted sublists/row + softmax (lax.top_k tie-break) ----
    if (tid < ROWS) {
        int r = tid;
#pragma unroll
        for (int s = 0; s < 8; ++s) Hd[r][s] = 0;
        float sel_s[8]; int sel_i[8];
#pragma unroll
        for (int k = 0; k < TOPK; ++k) {
            float bs = -INFINITY; int bi = 0x7fffffff; int bsub = 0;
            for (int s = 0; s < 8; ++s) {
                int hh = Hd[r][s];
                if (hh < 8) {
                    float cs = Ms[r][s][hh]; int ci = Mi[r][s][hh];
                    if (cs > bs || (cs == bs && ci < bi)) { bs = cs; bi = ci; bsub = s; }
                }
            }
            sel_s[k] = bs; sel_i[k] = bi; Hd[r][bsub]++;
        }
        float mx = sel_s[0];
        float w[8], z = 0.f;
#pragma unroll
        for (int k = 0; k < TOPK; ++k) { w[k] = __expf(sel_s[k] - mx); z += w[k]; }
        float inv = 1.f / z;
#pragma unroll
        for (int k = 0; k < TOPK; ++k) { Fs[r][k] = w[k] * inv; Fi[r][k] = sel_i[k]; }
    }
    __syncthreads();

    // ---- P3: weighted gather of values (fp32) -> AA[:, 256:512) ----
    {
        const int r = mrow, f0 = msub * 32;
        float rv[32];
#pragma unroll
        for (int t = 0; t < 32; ++t) rv[t] = 0.f;
        for (int jj = 0; jj < TOPK; ++jj) {
            float wgt = Fs[r][jj];
            int idx = Fi[r][jj] & (MSZ - 1);   // defensive: never OOB
            const float4* vp = (const float4*)(vals + (size_t)idx * 256 + f0);
#pragma unroll
            for (int vv = 0; vv < 8; ++vv) {
                float4 vb = vp[vv];
                rv[vv * 4 + 0] += wgt * vb.x;
                rv[vv * 4 + 1] += wgt * vb.y;
                rv[vv * 4 + 2] += wgt * vb.z;
                rv[vv * 4 + 3] += wgt * vb.w;
            }
        }
#pragma unroll
        for (int t = 0; t < 32; ++t) AA[r][256 + f0 + t] = (_Float16)rv[t];
    }
    __syncthreads();

    // ---- P4: h = relu([query|retrieved] @ W1 + b1) -> AA[:, 0:256) ----
    {
        f32x4 acc[2][4];
#pragma unroll
        for (int rt = 0; rt < 2; ++rt)
#pragma unroll
            for (int nt = 0; nt < 4; ++nt)
                acc[rt][nt] = (f32x4){0.f, 0.f, 0.f, 0.f};
#pragma unroll
        for (int kf = 0; kf < 16; ++kf) {
            f16x8 a0 = *(const f16x8*)&AA[l16][kf * 32 + quad * 8];
            f16x8 a1 = *(const f16x8*)&AA[l16 + 16][kf * 32 + quad * 8];
#pragma unroll
            for (int nt = 0; nt < 4; ++nt) {
                int n0 = wave * 16 + nt * 64;
                f16x8 b = *(const f16x8*)(W1T + (size_t)(n0 + l16) * 512 + kf * 32 + quad * 8);
                acc[0][nt] = MFMA(a0, b, acc[0][nt]);
                acc[1][nt] = MFMA(a1, b, acc[1][nt]);
            }
        }
        __syncthreads();  // drain all AA reads before overwriting cols 0:256
#pragma unroll
        for (int nt = 0; nt < 4; ++nt) {
            int col = wave * 16 + nt * 64 + l16;
            float bv = b1[col];
#pragma unroll
            for (int rt = 0; rt < 2; ++rt)
#pragma unroll
                for (int r = 0; r < 4; ++r)
                    AA[rt * 16 + quad * 4 + r][col] =
                        (_Float16)fmaxf(acc[rt][nt][r] + bv, 0.f);
        }
    }
    __syncthreads();

    // ---- P5: out = h @ W2 + b2 -> global (fp32) ----
    {
        f32x4 acc[2][4];
#pragma unroll
        for (int rt = 0; rt < 2; ++rt)
#pragma unroll
            for (int nt = 0; nt < 4; ++nt)
                acc[rt][nt] = (f32x4){0.f, 0.f, 0.f, 0.f};
#pragma unroll
        for (int kf = 0; kf < 8; ++kf) {
            f16x8 a0 = *(const f16x8*)&AA[l16][kf * 32 + quad * 8];
            f16x8 a1 = *(const f16x8*)&AA[l16 + 16][kf * 32 + quad * 8];
#pragma unroll
            for (int nt = 0; nt < 4; ++nt) {
                int n0 = wave * 16 + nt * 64;
                f16x8 b = *(const f16x8*)(W2T + (size_t)(n0 + l16) * 256 + kf * 32 + quad * 8);
                acc[0][nt] = MFMA(a0, b, acc[0][nt]);
                acc[1][nt] = MFMA(a1, b, acc[1][nt]);
            }
        }
#pragma unroll
        for (int nt = 0; nt < 4; ++nt) {
            int col = wave * 16 + nt * 64 + l16;
            float bv = b2[col];
#pragma unroll
            for (int rt = 0; rt < 2; ++rt)
#pragma unroll
                for (int r = 0; r < 4; ++r)
                    out[(row0 + rt * 16 + quad * 4 + r) * 256 + col] =
                        acc[rt][nt][r] + bv;
        }
    }
}

// ---------------------------------------------------------------------------
extern "C" void kernel_launch(void* const* d_in, const int* in_sizes, int n_in,
                              void* d_out, int out_size, void* d_ws, size_t ws_size,
                              hipStream_t stream) {
    const float* query = (const float*)d_in[0];
    const float* keys  = (const float*)d_in[1];
    const float* vals  = (const float*)d_in[2];
    const float* Wq    = (const float*)d_in[3];
    const float* bq    = (const float*)d_in[4];
    const float* W1    = (const float*)d_in[5];
    const float* b1    = (const float*)d_in[6];
    const float* W2    = (const float*)d_in[7];
    const float* b2    = (const float*)d_in[8];
    float* out = (float*)d_out;

    // ws layout (f16): keysH 2 MB @ 0 | WqT 128K | W1T 256K | W2T 128K = 2.5 MB
    char* ws = (char*)d_ws;
    _Float16* keysH = (_Float16*)(ws);
    _Float16* WqT   = (_Float16*)(ws + 2097152);
    _Float16* W1T   = (_Float16*)(ws + 2097152 + 131072);
    _Float16* W2T   = (_Float16*)(ws + 2097152 + 131072 + 262144);

    cvt_f16<<<4096, 256, 0, stream>>>(keys, keysH, MSZ * 256);
    cvt_transpose<<<256, 256, 0, stream>>>(Wq, WqT, 256, 256);
    cvt_transpose<<<512, 256, 0, stream>>>(W1, W1T, 512, 256);
    cvt_transpose<<<256, 256, 0, stream>>>(W2, W2T, 256, 256);

    fused_all<<<BN / 32, 256, 0, stream>>>(query, keysH, vals, WqT, bq,
                                           W1T, b1, W2T, b2, out);
}

// Round 6
// 857.016 us; speedup vs baseline: 2.6080x; 2.6080x over previous
//
#include <hip/hip_runtime.h>

typedef _Float16 f16x8 __attribute__((ext_vector_type(8)));
typedef _Float16 f16x4 __attribute__((ext_vector_type(4)));
typedef float f32x4 __attribute__((ext_vector_type(4)));

#define BN   65536   // B*N = 16*4096
#define MSZ  4096
#define TOPK 8

#define MFMA(a, b, c) __builtin_amdgcn_mfma_f32_16x16x32_f16(a, b, c, 0, 0, 0)

// ---------------------------------------------------------------------------
// Prep: fp32 -> fp16 flat convert (keys)
// ---------------------------------------------------------------------------
__global__ void cvt_f16(const float* __restrict__ src, _Float16* __restrict__ dst,
                        int n) {
    int i = blockIdx.x * 256 + threadIdx.x;
    if (i < n) dst[i] = (_Float16)src[i];
}

// ---------------------------------------------------------------------------
// Prep: dst[n*K + k] = (f16)src[k*N + n]
// ---------------------------------------------------------------------------
__global__ void cvt_transpose(const float* __restrict__ src, _Float16* __restrict__ dst,
                              int K, int N) {
    int i = blockIdx.x * 256 + threadIdx.x;
    if (i < K * N) {
        int k = i / N, n = i - k * N;
        dst[n * K + k] = (_Float16)src[i];
    }
}

// ---------------------------------------------------------------------------
// Packed selection key: [31:12] = ordered-uint fp32 score (truncated),
// [11:0] = ~idx (12 bits) -> bigger key = higher score, ties: lower idx wins.
// ---------------------------------------------------------------------------
__device__ __forceinline__ unsigned pack_key(float s, unsigned inv12) {
    unsigned u = __float_as_uint(s);
    unsigned m = (unsigned)(((int)u) >> 31) | 0x80000000u;
    unsigned k = u ^ m;                       // ordered mapping
    return (k & 0xFFFFF000u) | inv12;
}

// Branchless insert into sorted-descending list t[0..N-1] (u32, larger=better)
template <int N>
__device__ __forceinline__ void ins(unsigned* t, unsigned key) {
#pragma unroll
    for (int p = N - 1; p > 0; --p) {
        unsigned keep = (t[p] > key) ? t[p] : key;
        t[p] = (key >= t[p - 1]) ? t[p - 1] : keep;
    }
    t[0] = (t[0] > key) ? t[0] : key;
}

// ---------------------------------------------------------------------------
// Fully fused: proj -> sim -> top8 -> softmax -> gather -> MLP1 -> MLP2.
// 32 rows / block, 256 threads. Sim phase is BARRIER-FREE: each thread keeps
// top-6 packed keys per (row, col-slice) stream in registers; exact top-8 per
// row is rebuilt by a 3-stage LDS merge, then accurate fp32 scores are
// recomputed for softmax. fp32 in/out; f16 MFMA operands.
// ---------------------------------------------------------------------------
__global__ __launch_bounds__(256, 3) void fused_all(
        const float*    __restrict__ query,   // BN x 256 fp32
        const _Float16* __restrict__ keysH,   // 4096 x 256 f16 (ws)
        const float*    __restrict__ vals,    // 4096 x 256 fp32
        const _Float16* __restrict__ WqT,     // 256 x 256 f16 (ws, transposed)
        const float*    __restrict__ bq,
        const _Float16* __restrict__ W1T,     // 256 x 512 f16 (ws, transposed)
        const float*    __restrict__ b1,
        const _Float16* __restrict__ W2T,     // 256 x 256 f16 (ws, transposed)
        const float*    __restrict__ b2,
        float* __restrict__ out)              // BN x 256 fp32
{
    constexpr int ROWS = 32;
    __shared__ __attribute__((aligned(16))) _Float16 AA[ROWS][520];  // 33280 B
    __shared__ unsigned Ubuf[4608];                                  // 18432 B
    __shared__ float Fs[ROWS][TOPK];
    __shared__ int   Fi[ROWS][TOPK];

    const int tid  = threadIdx.x;
    const int lane = tid & 63, quad = lane >> 4, l16 = lane & 15, wave = tid >> 6;
    const size_t row0 = (size_t)blockIdx.x * ROWS;

    // ---- P0: stage 32 query rows (fp32 -> f16) into AA[:, 0:256) ----
    for (int v = tid; v < 2048; v += 256) {
        int r = v >> 6, c = (v & 63) * 4;
        float4 f = *(const float4*)(query + (row0 + r) * 256 + c);
        f16x4 h = {(_Float16)f.x, (_Float16)f.y, (_Float16)f.z, (_Float16)f.w};
        *(f16x4*)&AA[r][c] = h;
    }
    __syncthreads();

    // ---- P1: qproj = query @ Wq + bq -> AA[:, 256:512) ----
    {
        f32x4 acc[2][4];
#pragma unroll
        for (int rt = 0; rt < 2; ++rt)
#pragma unroll
            for (int nt = 0; nt < 4; ++nt)
                acc[rt][nt] = (f32x4){0.f, 0.f, 0.f, 0.f};
#pragma unroll
        for (int kf = 0; kf < 8; ++kf) {
            f16x8 a0 = *(const f16x8*)&AA[l16][kf * 32 + quad * 8];
            f16x8 a1 = *(const f16x8*)&AA[l16 + 16][kf * 32 + quad * 8];
#pragma unroll
            for (int nt = 0; nt < 4; ++nt) {
                int n0 = wave * 16 + nt * 64;
                f16x8 b = *(const f16x8*)(WqT + (size_t)(n0 + l16) * 256 + kf * 32 + quad * 8);
                acc[0][nt] = MFMA(a0, b, acc[0][nt]);
                acc[1][nt] = MFMA(a1, b, acc[1][nt]);
            }
        }
#pragma unroll
        for (int nt = 0; nt < 4; ++nt) {
            int col = wave * 16 + nt * 64 + l16;
            float bv = bq[col];
#pragma unroll
            for (int rt = 0; rt < 2; ++rt)
#pragma unroll
                for (int r = 0; r < 4; ++r)
                    AA[rt * 16 + quad * 4 + r][256 + col] = (_Float16)(acc[rt][nt][r] + bv);
        }
    }
    __syncthreads();

    // ---- P2: sim = qproj @ keys^T, barrier-free register top-6 per stream ----
    f16x8 af0[8], af1[8];
#pragma unroll
    for (int nk = 0; nk < 8; ++nk) {
        af0[nk] = *(const f16x8*)&AA[l16][256 + nk * 32 + quad * 8];
        af1[nk] = *(const f16x8*)&AA[l16 + 16][256 + nk * 32 + quad * 8];
    }

    unsigned tk[8][6];   // 8 streams: rows quad*4+r (0..3) and 16+quad*4+r (4..7)
#pragma unroll
    for (int s = 0; s < 8; ++s)
#pragma unroll
        for (int e = 0; e < 6; ++e) tk[s][e] = 0u;

    for (int m0 = 0; m0 < MSZ; m0 += 64) {
        f32x4 acc0 = {0.f, 0.f, 0.f, 0.f};
        f32x4 acc1 = {0.f, 0.f, 0.f, 0.f};
        const _Float16* bp = keysH + (size_t)(m0 + wave * 16 + l16) * 256 + quad * 8;
#pragma unroll
        for (int nk = 0; nk < 8; ++nk) {
            f16x8 b = *(const f16x8*)(bp + nk * 32);
            acc0 = MFMA(af0[nk], b, acc0);
            acc1 = MFMA(af1[nk], b, acc1);
        }
        unsigned inv12 = (~(unsigned)(m0 + wave * 16 + l16)) & 0xFFFu;
#pragma unroll
        for (int r = 0; r < 4; ++r) ins<6>(tk[r],     pack_key(acc0[r], inv12));
#pragma unroll
        for (int r = 0; r < 4; ++r) ins<6>(tk[4 + r], pack_key(acc1[r], inv12));
    }

    // ---- merge: 4 quad-groups; per group: dump -> 12->6 -> 24->8 -> 64->8 ----
    for (int g = 0; g < 4; ++g) {
        __syncthreads();                       // Ubuf reuse across groups
        if (quad == g) {
            int slice = wave * 16 + l16;
#pragma unroll
            for (int rl = 0; rl < 8; ++rl)
#pragma unroll
                for (int e = 0; e < 6; ++e)
                    Ubuf[(rl * 64 + slice) * 6 + e] = tk[rl][e];
        }
        __syncthreads();
        // stage1: 256 threads, each merges 2 slices (12 entries) -> top6
        {
            int rl = tid >> 5, part = tid & 31;
            unsigned s1[6];
#pragma unroll
            for (int e = 0; e < 6; ++e) s1[e] = 0u;
            for (int sl = 2 * part; sl < 2 * part + 2; ++sl)
#pragma unroll
                for (int e = 0; e < 6; ++e)
                    ins<6>(s1, Ubuf[(rl * 64 + sl) * 6 + e]);
#pragma unroll
            for (int e = 0; e < 6; ++e)
                Ubuf[3072 + (rl * 32 + part) * 6 + e] = s1[e];   // disjoint region
        }
        __syncthreads();
        // stage2: 64 threads, each merges 4 stage1 lists (24) -> top8
        if (tid < 64) {
            int rl = tid >> 3, p8 = tid & 7;
            unsigned s2[8];
#pragma unroll
            for (int e = 0; e < 8; ++e) s2[e] = 0u;
            for (int q = 0; q < 4; ++q)
#pragma unroll
                for (int e = 0; e < 6; ++e)
                    ins<8>(s2, Ubuf[3072 + (rl * 32 + p8 * 4 + q) * 6 + e]);
#pragma unroll
            for (int e = 0; e < 8; ++e)
                Ubuf[(rl * 8 + p8) * 8 + e] = s2[e];             // over dump region
        }
        __syncthreads();
        // stage3: 8 threads, each merges 8 stage2 lists (64) -> final top8
        if (tid < 8) {
            unsigned s3[8];
#pragma unroll
            for (int e = 0; e < 8; ++e) s3[e] = 0u;
            for (int i = 0; i < 64; ++i) ins<8>(s3, Ubuf[tid * 64 + i]);
            int row = (tid < 4) ? (g * 4 + tid) : (16 + g * 4 + (tid - 4));
#pragma unroll
            for (int k = 0; k < TOPK; ++k)
                Fi[row][k] = 4095 - (int)(s3[k] & 0xFFFu);
        }
    }
    __syncthreads();

    // ---- recompute accurate fp32 scores + softmax weights ----
    {
        int r = tid >> 3, j = tid & 7;
        int idx = Fi[r][j] & (MSZ - 1);
        const f16x8* kp = (const f16x8*)(keysH + (size_t)idx * 256);
        float s = 0.f;
#pragma unroll
        for (int v = 0; v < 32; ++v) {
            f16x8 kv = kp[v];
            f16x8 qv = *(const f16x8*)&AA[r][256 + v * 8];
#pragma unroll
            for (int e = 0; e < 8; ++e) s += (float)qv[e] * (float)kv[e];
        }
        float mx = s;
#pragma unroll
        for (int off = 1; off < 8; off <<= 1) mx = fmaxf(mx, __shfl_xor(mx, off));
        float w = __expf(s - mx);
        float z = w;
#pragma unroll
        for (int off = 1; off < 8; off <<= 1) z += __shfl_xor(z, off);
        Fs[r][j] = w / z;
    }
    __syncthreads();

    // ---- P3: weighted gather of values (fp32) -> AA[:, 256:512) ----
    {
        const int r = tid >> 3, f0 = (tid & 7) * 32;
        float rv[32];
#pragma unroll
        for (int t = 0; t < 32; ++t) rv[t] = 0.f;
        for (int jj = 0; jj < TOPK; ++jj) {
            float wgt = Fs[r][jj];
            int idx = Fi[r][jj] & (MSZ - 1);
            const float4* vp = (const float4*)(vals + (size_t)idx * 256 + f0);
#pragma unroll
            for (int vv = 0; vv < 8; ++vv) {
                float4 vb = vp[vv];
                rv[vv * 4 + 0] += wgt * vb.x;
                rv[vv * 4 + 1] += wgt * vb.y;
                rv[vv * 4 + 2] += wgt * vb.z;
                rv[vv * 4 + 3] += wgt * vb.w;
            }
        }
#pragma unroll
        for (int t = 0; t < 32; ++t) AA[r][256 + f0 + t] = (_Float16)rv[t];
    }
    __syncthreads();

    // ---- P4: h = relu([query|retrieved] @ W1 + b1) -> AA[:, 0:256) ----
    {
        f32x4 acc[2][4];
#pragma unroll
        for (int rt = 0; rt < 2; ++rt)
#pragma unroll
            for (int nt = 0; nt < 4; ++nt)
                acc[rt][nt] = (f32x4){0.f, 0.f, 0.f, 0.f};
#pragma unroll
        for (int kf = 0; kf < 16; ++kf) {
            f16x8 a0 = *(const f16x8*)&AA[l16][kf * 32 + quad * 8];
            f16x8 a1 = *(const f16x8*)&AA[l16 + 16][kf * 32 + quad * 8];
#pragma unroll
            for (int nt = 0; nt < 4; ++nt) {
                int n0 = wave * 16 + nt * 64;
                f16x8 b = *(const f16x8*)(W1T + (size_t)(n0 + l16) * 512 + kf * 32 + quad * 8);
                acc[0][nt] = MFMA(a0, b, acc[0][nt]);
                acc[1][nt] = MFMA(a1, b, acc[1][nt]);
            }
        }
        __syncthreads();  // drain AA reads before overwriting cols 0:256
#pragma unroll
        for (int nt = 0; nt < 4; ++nt) {
            int col = wave * 16 + nt * 64 + l16;
            float bv = b1[col];
#pragma unroll
            for (int rt = 0; rt < 2; ++rt)
#pragma unroll
                for (int r = 0; r < 4; ++r)
                    AA[rt * 16 + quad * 4 + r][col] =
                        (_Float16)fmaxf(acc[rt][nt][r] + bv, 0.f);
        }
    }
    __syncthreads();

    // ---- P5: out = h @ W2 + b2 -> global (fp32) ----
    {
        f32x4 acc[2][4];
#pragma unroll
        for (int rt = 0; rt < 2; ++rt)
#pragma unroll
            for (int nt = 0; nt < 4; ++nt)
                acc[rt][nt] = (f32x4){0.f, 0.f, 0.f, 0.f};
#pragma unroll
        for (int kf = 0; kf < 8; ++kf) {
            f16x8 a0 = *(const f16x8*)&AA[l16][kf * 32 + quad * 8];
            f16x8 a1 = *(const f16x8*)&AA[l16 + 16][kf * 32 + quad * 8];
#pragma unroll
            for (int nt = 0; nt < 4; ++nt) {
                int n0 = wave * 16 + nt * 64;
                f16x8 b = *(const f16x8*)(W2T + (size_t)(n0 + l16) * 256 + kf * 32 + quad * 8);
                acc[0][nt] = MFMA(a0, b, acc[0][nt]);
                acc[1][nt] = MFMA(a1, b, acc[1][nt]);
            }
        }
#pragma unroll
        for (int nt = 0; nt < 4; ++nt) {
            int col = wave * 16 + nt * 64 + l16;
            float bv = b2[col];
#pragma unroll
            for (int rt = 0; rt < 2; ++rt)
#pragma unroll
                for (int r = 0; r < 4; ++r)
                    out[(row0 + rt * 16 + quad * 4 + r) * 256 + col] =
                        acc[rt][nt][r] + bv;
        }
    }
}

// ---------------------------------------------------------------------------
extern "C" void kernel_launch(void* const* d_in, const int* in_sizes, int n_in,
                              void* d_out, int out_size, void* d_ws, size_t ws_size,
                              hipStream_t stream) {
    const float* query = (const float*)d_in[0];
    const float* keys  = (const float*)d_in[1];
    const float* vals  = (const float*)d_in[2];
    const float* Wq    = (const float*)d_in[3];
    const float* bq    = (const float*)d_in[4];
    const float* W1    = (const float*)d_in[5];
    const float* b1    = (const float*)d_in[6];
    const float* W2    = (const float*)d_in[7];
    const float* b2    = (const float*)d_in[8];
    float* out = (float*)d_out;

    // ws layout (f16): keysH 2 MB @ 0 | WqT 128K | W1T 256K | W2T 128K = 2.5 MB
    char* ws = (char*)d_ws;
    _Float16* keysH = (_Float16*)(ws);
    _Float16* WqT   = (_Float16*)(ws + 2097152);
    _Float16* W1T   = (_Float16*)(ws + 2097152 + 131072);
    _Float16* W2T   = (_Float16*)(ws + 2097152 + 131072 + 262144);

    cvt_f16<<<4096, 256, 0, stream>>>(keys, keysH, MSZ * 256);
    cvt_transpose<<<256, 256, 0, stream>>>(Wq, WqT, 256, 256);
    cvt_transpose<<<512, 256, 0, stream>>>(W1, W1T, 512, 256);
    cvt_transpose<<<256, 256, 0, stream>>>(W2, W2T, 256, 256);

    fused_all<<<BN / 32, 256, 0, stream>>>(query, keysH, vals, WqT, bq,
                                           W1T, b1, W2T, b2, out);
}